// Round 5
// baseline (64.661 us; speedup 1.0000x reference)
//
#include <hip/hip_runtime.h>

// Chamfer distance, fp32 brute force, VALU-bound.
// rows 0..32767    : predict points (b = r>>13), cols = target[b]
// rows 32768..65535: target points,              cols = predict[b]
// Per row: min over 8192 cols of (||t||^2 - 2 p.t), then + ||p||^2.
// out = (sum over all 65536 rows) / 32768.
//
// Column data is wave-uniform -> loaded via the SCALAR path (s_load into
// SGPRs, uniform blockIdx-derived addresses), no LDS at all (R3 showed the
// LDS pipe at ~86% of VALU time: ds_read_b128=12cyc x 4/iter x 32 waves/CU
// was the stall source pinning minpart at ~43us across 3 codegens).
// Inner: q=-2p per row; s = fma(qx,tx, fma(qy,ty, fma(qz,tz, tw)));
// v_min3_f32 folds 2 cols. 3.625 VALU/pair -> ~25us floor.
// Cross-chunk combine: deterministic atomicMin on monotone uint keys.

#define NPTS   8192
#define HALF   32768            // 4 * NPTS
#define NROWS  65536
#define P      8                // rows per thread (32 VGPR row state)
#define RPB    2048             // rows per block = 256 * P
#define NRB    32               // NROWS / RPB
#define NCH    64               // col chunks -> 2048 blocks = 8/CU
#define CW     (NPTS / NCH)     // 128 cols per chunk

__device__ __forceinline__ float min3f(float a, float b, float c) {
    float d;
    asm("v_min3_f32 %0, %1, %2, %3" : "=v"(d) : "v"(a), "v"(b), "v"(c));
    return d;
}

// float -> order-preserving uint (for atomicMin)
__device__ __forceinline__ unsigned int fkey(float f) {
    unsigned int b = __float_as_uint(f);
    return (b & 0x80000000u) ? ~b : (b | 0x80000000u);
}
__device__ __forceinline__ float funkey(unsigned int k) {
    unsigned int b = (k & 0x80000000u) ? (k ^ 0x80000000u) : ~k;
    return __uint_as_float(b);
}

__global__ __launch_bounds__(256) void pack_kernel(
    const float* __restrict__ predict, const float* __restrict__ target,
    float4* __restrict__ packed, unsigned int* __restrict__ rowmin)
{
    int r = blockIdx.x * 256 + threadIdx.x;
    const float* src = (r < HALF) ? (predict + (size_t)r * 3)
                                  : (target + (size_t)(r - HALF) * 3);
    float x = src[0], y = src[1], z = src[2];
    float nrm = fmaf(x, x, fmaf(y, y, z * z));
    packed[r] = make_float4(x, y, z, nrm);
    rowmin[r] = 0xFFFFFFFFu;                  // +inf key
}

__global__ __launch_bounds__(256) void minpart_kernel(
    const float4* __restrict__ packed, unsigned int* __restrict__ rowmin)
{
    const int rb   = blockIdx.x / NCH;
    const int cb   = blockIdx.x % NCH;
    const int row0 = rb * RPB;
    const bool sideA = (row0 < HALF);
    const int local = sideA ? row0 : row0 - HALF;
    const int b = local >> 13;                // / NPTS
    // uniform column pointer -> scalar loads (s_load) via K$
    const float4* __restrict__ col =
        packed + ((sideA ? HALF : 0) + (b << 13) + cb * CW);

    float qx[P], qy[P], qz[P], mn[P];
    #pragma unroll
    for (int j = 0; j < P; ++j) {
        float4 p = packed[row0 + threadIdx.x + j * 256];
        qx[j] = -2.0f * p.x; qy[j] = -2.0f * p.y; qz[j] = -2.0f * p.z;
        mn[j] = 3.4e38f;
    }

    #pragma unroll 1
    for (int i = 0; i < CW; i += 4) {
        float4 t0 = col[i + 0];               // uniform -> s_load_dwordx4
        float4 t1 = col[i + 1];
        float4 t2 = col[i + 2];
        float4 t3 = col[i + 3];
        #pragma unroll
        for (int j = 0; j < P; ++j) {
            float s0 = fmaf(qx[j], t0.x, fmaf(qy[j], t0.y, fmaf(qz[j], t0.z, t0.w)));
            float s1 = fmaf(qx[j], t1.x, fmaf(qy[j], t1.y, fmaf(qz[j], t1.z, t1.w)));
            float s2 = fmaf(qx[j], t2.x, fmaf(qy[j], t2.y, fmaf(qz[j], t2.z, t2.w)));
            float s3 = fmaf(qx[j], t3.x, fmaf(qy[j], t3.y, fmaf(qz[j], t3.z, t3.w)));
            mn[j] = min3f(mn[j], s0, s1);
            mn[j] = min3f(mn[j], s2, s3);
        }
    }

    #pragma unroll
    for (int j = 0; j < P; ++j)
        atomicMin(&rowmin[row0 + threadIdx.x + j * 256], fkey(mn[j]));
}

__global__ __launch_bounds__(256) void reduce_kernel(
    const float4* __restrict__ packed, const unsigned int* __restrict__ rowmin,
    float* __restrict__ blockSums)
{
    int r = blockIdx.x * 256 + threadIdx.x;
    float val = funkey(rowmin[r]) + packed[r].w;   // + ||p||^2

    __shared__ float red[256];
    red[threadIdx.x] = val;
    __syncthreads();
    for (int s = 128; s > 0; s >>= 1) {
        if (threadIdx.x < s) red[threadIdx.x] += red[threadIdx.x + s];
        __syncthreads();
    }
    if (threadIdx.x == 0) blockSums[blockIdx.x] = red[0];
}

__global__ __launch_bounds__(256) void final_kernel(
    const float* __restrict__ blockSums, float* __restrict__ out)
{
    __shared__ float red[256];
    red[threadIdx.x] = blockSums[threadIdx.x];
    __syncthreads();
    for (int s = 128; s > 0; s >>= 1) {
        if (threadIdx.x < s) red[threadIdx.x] += red[threadIdx.x + s];
        __syncthreads();
    }
    if (threadIdx.x == 0) out[0] = red[0] * (1.0f / (float)HALF);
}

extern "C" void kernel_launch(void* const* d_in, const int* in_sizes, int n_in,
                              void* d_out, int out_size, void* d_ws, size_t ws_size,
                              hipStream_t stream)
{
    const float* predict = (const float*)d_in[0];
    const float* target  = (const float*)d_in[1];
    float* out = (float*)d_out;

    char* ws = (char*)d_ws;
    float4*       packed    = (float4*)ws;                              // 1 MB
    unsigned int* rowmin    = (unsigned int*)(ws + (size_t)NROWS * 16); // 256 KB
    float*        blockSums = (float*)(ws + (size_t)NROWS * 16
                                          + (size_t)NROWS * 4);         // 1 KB

    pack_kernel   <<<NROWS / 256, 256, 0, stream>>>(predict, target, packed, rowmin);
    minpart_kernel<<<NRB * NCH,   256, 0, stream>>>(packed, rowmin);
    reduce_kernel <<<NROWS / 256, 256, 0, stream>>>(packed, rowmin, blockSums);
    final_kernel  <<<1,           256, 0, stream>>>(blockSums, out);
}